// Round 23
// baseline (81.680 us; speedup 1.0000x reference)
//
#include <hip/hip_runtime.h>
#include <hip/hip_fp16.h>
#include <math.h>

#define HH   128
#define WW   128
#define HWP  16384      // H*W
#define CIN  64
#define COUT 128

typedef float  f32x4  __attribute__((ext_vector_type(4)));
typedef short  short8 __attribute__((ext_vector_type(8)));

// ws layout (bytes): wbf [128][576] bf16 @0; owbf [32][576] bf16 @147456;
// xt NHWC bf16 @221184 (8388608); meta fp16 [27][4][16384] @8609792 (3538944).
#define WBF_B    ((size_t)0)
#define OWBF_B   ((size_t)147456)
#define XT_B     ((size_t)221184)
#define META_B   ((size_t)8609792)
#define WS_NEED  ((size_t)8609792)
#define WS_NEED3 ((size_t)12148736)

__device__ inline unsigned short f2bf(float f) {
    unsigned u = __builtin_bit_cast(unsigned, f);
    return (unsigned short)((u + 0x7FFFu + ((u >> 16) & 1u)) >> 16);   // RNE
}

// ---------------- fused prep: xt transpose + weight transposes ----------------
__global__ __launch_bounds__(256) void k_prep(const float* __restrict__ x,
                                              const float* __restrict__ wgt,
                                              const float* __restrict__ ow,
                                              unsigned short* __restrict__ xt,
                                              unsigned short* __restrict__ wbf,
                                              unsigned short* __restrict__ owbf) {
    int t = threadIdx.x;
    if (blockIdx.x < 2048) {
        int bid  = blockIdx.x;
        int bid2 = (bid & 7) * 256 + (bid >> 3);      // T1 chunking (bijective)
        int cgrp = t & 7, px = t >> 3;
        int pix = bid2 * 32 + px;
        int b = pix >> 14, hw = pix & 16383;
        const float* xp = x + (size_t)b * CIN * HWP + (size_t)(cgrp * 8) * HWP + hw;
        unsigned pk[4];
#pragma unroll
        for (int d = 0; d < 4; ++d) {
            float lo = xp[(size_t)(2 * d) * HWP];
            float hi = xp[(size_t)(2 * d + 1) * HWP];
            pk[d] = (unsigned)f2bf(lo) | ((unsigned)f2bf(hi) << 16);
        }
        *(uint4*)(xt + (size_t)pix * 64 + cgrp * 8) = *(uint4*)pk;
    } else {
        int tid = (blockIdx.x - 2048) * 256 + t;
        {
            int oc = tid / 576;
            int r  = tid - oc * 576;
            int kk = r >> 6;
            int c  = r & 63;
            wbf[tid] = f2bf(wgt[((size_t)oc * CIN + c) * 9 + kk]);
        }
        if (tid < 32 * 576) {
            int oc  = tid / 576;
            int r   = tid - oc * 576;
            int tap = r >> 6;
            int c   = r & 63;
            owbf[tid] = (oc < 27) ? f2bf(ow[((size_t)oc * CIN + c) * 9 + tap]) : 0;
        }
    }
}

// ---------------- offset conv v3: LDS-staged context (proven R22) ----------
__global__ __launch_bounds__(256) void k_offc(const unsigned short* __restrict__ xt,
                                              const unsigned short* __restrict__ owbf,
                                              const float* __restrict__ ob,
                                              __half* __restrict__ meta_h) {
    __shared__ __align__(16) char ctx[13056];

    int blk0 = blockIdx.x;                       // 2048
    int blk  = (blk0 & 7) * 256 + (blk0 >> 3);   // T1 XCD chunking
    int b   = blk >> 9;
    int rem = blk & 511;
    int h   = rem >> 2;
    int w0  = (rem & 3) << 5;
    int t   = threadIdx.x;
    int l   = t & 63;
    int wid = t >> 6;
    int lm  = l & 15, lk = l >> 4;

    const unsigned short* xbt = xt + (size_t)b * HWP * 64;

#pragma unroll
    for (int c = 0; c < 4; ++c) {
        int j = c * 256 + t;
        if (j < 816) {
            int g   = j / 34;
            int px  = j - g * 34;
            int row = g >> 3;
            int cgj = g & 7;
            int yy = h - 1 + row;
            int xx = w0 - 1 + px;
            bool vld = (yy >= 0) && (yy < HH) && (xx >= 0) && (xx < WW);
            uint4 v = {0u, 0u, 0u, 0u};
            if (vld) v = *(const uint4*)(xbt + (size_t)(yy * WW + xx) * 64 + cgj * 8);
            *(uint4*)(ctx + (row * 34 + px) * 128 + ((cgj ^ (px & 7)) << 4)) = v;
        }
    }
    __syncthreads();

    int ocf = wid >> 1, pxf = wid & 1;
    int spx = pxf * 16 + lm;
    f32x4 sacc = {0.f, 0.f, 0.f, 0.f};
    const unsigned short* sab = owbf + (size_t)(ocf * 16 + lm) * 576 + lk * 8;

#pragma unroll
    for (int tap = 0; tap < 9; ++tap) {
        int ky = tap / 3, kx = tap % 3;
        int cpx = kx + spx;
        int crb = (ky * 34 + cpx) * 128;
        int csw = cpx & 7;
#pragma unroll
        for (int ch = 0; ch < 2; ++ch) {
            short8 a  = *(const short8*)(sab + tap * 64 + ch * 32);
            int kb = ch * 4 + lk;
            short8 bf = *(const short8*)(ctx + crb + (((unsigned)(kb ^ csw)) << 4));
            sacc = __builtin_amdgcn_mfma_f32_16x16x32_bf16(a, bf, sacc, 0, 0, 0);
        }
    }
    int hw = h * WW + w0 + spx;
#pragma unroll
    for (int q = 0; q < 4; ++q) {
        int oc = ocf * 16 + lk * 4 + q;
        if (oc < 27) {
            float v = sacc[q] + ob[oc];
            int comp, kk;
            if (oc < 18) { comp = oc & 1; kk = oc >> 1; }
            else         { comp = 2; kk = oc - 18; v = 1.f / (1.f + expf(-v)); }
            meta_h[((size_t)(comp * 9 + kk) * 4 + b) * HWP + hw] = __float2half(v);
        }
    }
}

// ================= k_main64: 64px x 128oc, 512 threads, 8 waves ==============
// A-frag L2 traffic per px halved (16KB/round serves 64px); 9 rounds amortize
// over 2x work; LDS 23.3KB -> 4 blocks/CU x 8 waves = 32 waves (full).
__global__ __launch_bounds__(512) void k_main64(const unsigned short* __restrict__ xt,
                                                const unsigned short* __restrict__ wbf,
                                                const __half* __restrict__ meta_h,
                                                const float* __restrict__ bias,
                                                float* __restrict__ out) {
    __shared__ __align__(16) char smem[23296];
    char*  mbase  = smem;                     // 2 x 8KB bf16 [64p][64k] swizzled dbuf
    float* meta_s = (float*)(smem + 16384);   // [comp][kk][64p] 6912B

    int blk0 = blockIdx.x;                    // 1024
    int blk  = (blk0 & 7) * 128 + (blk0 >> 3);   // T1 XCD chunking (1024%8==0)
    int b   = blk >> 8;
    int rem = blk & 255;
    int h   = rem >> 1;
    int w0  = (rem & 1) << 6;
    int t   = threadIdx.x;

    int p1 = t >> 3;                          // pixel 0..63 (staging role)
    int cg = t & 7;                           // 8-ch group (staging role)
    int l  = t & 63;
    int wid = t >> 6;                         // wave 0..7
    int lm = l & 15, lk = l >> 4;
    int ocg = wid >> 1;                       // 32-oc group 0..3
    int pxh = wid & 1;                        // px half 0/1

    const unsigned short* xbt = xt + (size_t)b * HWP * 64;

    // ---- stage meta for 64 px (1728 fp16 -> fp32) ----
    {
        int base_hw = h * WW + w0;
        for (int j = t; j < 1728; j += 512) {
            int px = j & 63;
            int ck = j >> 6;                  // comp*9+kk, 0..26
            float v = __half2float(meta_h[((size_t)ck * 4 + b) * HWP + base_hw + px]);
            int comp = ck / 9, kk = ck - comp * 9;
            meta_s[comp * 576 + kk * 64 + px] = v;
        }
    }
    __syncthreads();

    f32x4 acc00 = {0.f,0.f,0.f,0.f};
    f32x4 acc01 = {0.f,0.f,0.f,0.f};
    f32x4 acc10 = {0.f,0.f,0.f,0.f};
    f32x4 acc11 = {0.f,0.f,0.f,0.f};

    const unsigned short* arow0 = wbf + (size_t)(ocg * 32 + lm) * 576 + lk * 8;
    const unsigned short* arow1 = arow0 + 16 * 576;

    int pA = pxh * 32 + lm, pB = pA + 16;
    int rbA = pA * 128, rbB = pB * 128;
    int swA = pA & 7,   swB = pB & 7;

    uint4 cc00, cc01, cc10, cc11;
    float cw00, cw01, cw10, cw11;

    const unsigned short* xbc = xbt + cg * 8;

#define PREF_CORNERS(KK) do {                                                  \
      int ky_ = (KK) / 3, kx_ = (KK) % 3;                                      \
      float offy = meta_s[(KK) * 64 + p1];                                     \
      float offx = meta_s[576 + (KK) * 64 + p1];                               \
      float msk  = meta_s[1152 + (KK) * 64 + p1];                              \
      float py = (float)(h - 1 + ky_) + offy;                                  \
      float px = (float)(w0 + p1 - 1 + kx_) + offx;                            \
      float y0f = floorf(py), x0f = floorf(px);                                \
      float ly = py - y0f, lx = px - x0f;                                      \
      int y0 = (int)y0f, x0i = (int)x0f;                                       \
      int y1 = y0 + 1, x1 = x0i + 1;                                           \
      bool vy0 = (y0 >= 0) && (y0 < HH);                                       \
      bool vy1 = (y1 >= 0) && (y1 < HH);                                       \
      bool vx0 = (x0i >= 0) && (x0i < WW);                                     \
      bool vx1 = (x1 >= 0) && (x1 < WW);                                       \
      int yc0 = min(max(y0, 0), HH - 1), yc1 = min(max(y1, 0), HH - 1);        \
      int xc0 = min(max(x0i, 0), WW - 1), xc1 = min(max(x1, 0), WW - 1);       \
      cw00 = (1.f - ly) * (1.f - lx) * ((vy0 && vx0) ? msk : 0.f);             \
      cw01 = (1.f - ly) * lx         * ((vy0 && vx1) ? msk : 0.f);             \
      cw10 = ly * (1.f - lx)         * ((vy1 && vx0) ? msk : 0.f);             \
      cw11 = ly * lx                 * ((vy1 && vx1) ? msk : 0.f);             \
      cc00 = *(const uint4*)(xbc + (size_t)(yc0 * WW + xc0) * 64);             \
      cc01 = *(const uint4*)(xbc + (size_t)(yc0 * WW + xc1) * 64);             \
      cc10 = *(const uint4*)(xbc + (size_t)(yc1 * WW + xc0) * 64);             \
      cc11 = *(const uint4*)(xbc + (size_t)(yc1 * WW + xc1) * 64);             \
    } while (0)

    PREF_CORNERS(0);

#pragma unroll
    for (int kk = 0; kk < 9; ++kk) {
        const int cur = kk & 1;
        {
            char* wdst = mbase + cur * 8192;
            unsigned pk[4];
#pragma unroll
            for (int d = 0; d < 4; ++d) {
                unsigned u0 = (&cc00.x)[d], u1 = (&cc01.x)[d];
                unsigned u2 = (&cc10.x)[d], u3 = (&cc11.x)[d];
                float lo = cw00 * __builtin_bit_cast(float, u0 << 16)
                         + cw01 * __builtin_bit_cast(float, u1 << 16)
                         + cw10 * __builtin_bit_cast(float, u2 << 16)
                         + cw11 * __builtin_bit_cast(float, u3 << 16);
                float hi = cw00 * __builtin_bit_cast(float, u0 & 0xFFFF0000u)
                         + cw01 * __builtin_bit_cast(float, u1 & 0xFFFF0000u)
                         + cw10 * __builtin_bit_cast(float, u2 & 0xFFFF0000u)
                         + cw11 * __builtin_bit_cast(float, u3 & 0xFFFF0000u);
                pk[d] = (unsigned)f2bf(lo) | ((unsigned)f2bf(hi) << 16);
            }
            *(uint4*)(wdst + p1 * 128 + (((unsigned)(cg ^ (p1 & 7))) << 4)) = *(uint4*)pk;
        }
        if (kk < 8) PREF_CORNERS(kk + 1);
        asm volatile("s_waitcnt lgkmcnt(0)" ::: "memory");
        __builtin_amdgcn_s_barrier();
        __builtin_amdgcn_sched_barrier(0);
        const char* rb = mbase + cur * 8192;
#pragma unroll
        for (int sstep = 0; sstep < 2; ++sstep) {
            short8 a0 = *(const short8*)(arow0 + kk * 64 + sstep * 32);
            short8 a1 = *(const short8*)(arow1 + kk * 64 + sstep * 32);
            int kb = sstep * 4 + lk;
            short8 b0 = *(const short8*)(rb + rbA + ((kb ^ swA) << 4));
            short8 b1 = *(const short8*)(rb + rbB + ((kb ^ swB) << 4));
            acc00 = __builtin_amdgcn_mfma_f32_16x16x32_bf16(a0, b0, acc00, 0, 0, 0);
            acc01 = __builtin_amdgcn_mfma_f32_16x16x32_bf16(a0, b1, acc01, 0, 0, 0);
            acc10 = __builtin_amdgcn_mfma_f32_16x16x32_bf16(a1, b0, acc10, 0, 0, 0);
            acc11 = __builtin_amdgcn_mfma_f32_16x16x32_bf16(a1, b1, acc11, 0, 0, 0);
        }
    }
#undef PREF_CORNERS

    // ---- epilogue (C map: col=lane&15 -> px, row=lk*4+q -> oc) ----
    size_t outb = (size_t)b * COUT * HWP + (size_t)h * WW + w0;
#pragma unroll
    for (int of = 0; of < 2; ++of) {
        f32x4 aP = of ? acc10 : acc00;
        f32x4 aQ = of ? acc11 : acc01;
        int ocb = ocg * 32 + of * 16 + lk * 4;
#pragma unroll
        for (int q = 0; q < 4; ++q) {
            int oc = ocb + q;
            float bi = bias[oc];
            out[outb + (size_t)oc * HWP + pA] = aP[q] + bi;
            out[outb + (size_t)oc * HWP + pB] = aQ[q] + bi;
        }
    }
}

// ================= v2 fused (R17 exact; fallback if ws too small) ============
__global__ __launch_bounds__(256) void k_fused_v2(const unsigned short* __restrict__ xt,
                                                  const unsigned short* __restrict__ wbf,
                                                  const unsigned short* __restrict__ owbf,
                                                  const float* __restrict__ ob,
                                                  const float* __restrict__ bias,
                                                  float* __restrict__ out) {
    __shared__ __align__(16) char smem[11648];
    char*  mbase  = smem;
    float* meta_s = (float*)(smem + 8192);

    int blk0 = blockIdx.x;
    int blk  = (blk0 & 7) * 256 + (blk0 >> 3);
    int b   = blk >> 9;
    int rem = blk & 511;
    int h   = rem >> 2;
    int w0  = (rem & 3) << 5;
    int t   = threadIdx.x;

    int p1 = t >> 3;
    int cg = t & 7;
    int l  = t & 63;
    int wid = t >> 6;
    int lm = l & 15, lk = l >> 4;

    const unsigned short* xbt = xt + (size_t)b * HWP * 64;

    int ocf = wid >> 1, pxf = wid & 1;
    int spx = pxf * 16 + lm;
    f32x4 sacc = {0.f, 0.f, 0.f, 0.f};
    const unsigned short* sab = owbf + (size_t)(ocf * 16 + lm) * 576 + lk * 8;

#pragma unroll
    for (int tap = 0; tap < 9; ++tap) {
        int ky = tap / 3, kx = tap % 3;
        int yy = h - 1 + ky;
        int xx = w0 - 1 + kx + spx;
        bool vld = (yy >= 0) && (yy < HH) && (xx >= 0) && (xx < WW);
        int yc = min(max(yy, 0), HH - 1), xc = min(max(xx, 0), WW - 1);
        const unsigned short* bp = xbt + (size_t)(yc * WW + xc) * 64 + lk * 8;
#pragma unroll
        for (int ch = 0; ch < 2; ++ch) {
            short8 a = *(const short8*)(sab + tap * 64 + ch * 32);
            uint4 v = *(const uint4*)(bp + ch * 32);
            v.x = vld ? v.x : 0u;  v.y = vld ? v.y : 0u;
            v.z = vld ? v.z : 0u;  v.w = vld ? v.w : 0u;
            sacc = __builtin_amdgcn_mfma_f32_16x16x32_bf16(a, __builtin_bit_cast(short8, v), sacc, 0, 0, 0);
        }
    }
#pragma unroll
    for (int q = 0; q < 4; ++q) {
        int oc = ocf * 16 + lk * 4 + q;
        if (oc < 27) {
            float v = sacc[q] + ob[oc];
            if (oc < 18) {
                meta_s[(oc & 1) * 288 + (oc >> 1) * 32 + spx] = v;
            } else {
                meta_s[2 * 288 + (oc - 18) * 32 + spx] = 1.f / (1.f + expf(-v));
            }
        }
    }
    __syncthreads();

    f32x4 acc00 = {0.f,0.f,0.f,0.f};
    f32x4 acc01 = {0.f,0.f,0.f,0.f};
    f32x4 acc10 = {0.f,0.f,0.f,0.f};
    f32x4 acc11 = {0.f,0.f,0.f,0.f};

    const unsigned short* arow0 = wbf + (size_t)(wid * 32 + lm) * 576 + lk * 8;
    const unsigned short* arow1 = arow0 + 16 * 576;

    int pA = lm, pB = lm + 16;
    int rbA = pA * 128, rbB = pB * 128;
    int swA = pA & 7,   swB = pB & 7;

    uint4 cc00, cc01, cc10, cc11;
    float cw00, cw01, cw10, cw11;

    const unsigned short* xbc = xbt + cg * 8;

#define PREF_CORNERS(KK) do {                                                  \
      int ky_ = (KK) / 3, kx_ = (KK) % 3;                                      \
      float offy = meta_s[(KK) * 32 + p1];                                     \
      float offx = meta_s[288 + (KK) * 32 + p1];                               \
      float msk  = meta_s[576 + (KK) * 32 + p1];                               \
      float py = (float)(h - 1 + ky_) + offy;                                  \
      float px = (float)(w0 + p1 - 1 + kx_) + offx;                            \
      float y0f = floorf(py), x0f = floorf(px);                                \
      float ly = py - y0f, lx = px - x0f;                                      \
      int y0 = (int)y0f, x0i = (int)x0f;                                       \
      int y1 = y0 + 1, x1 = x0i + 1;                                           \
      bool vy0 = (y0 >= 0) && (y0 < HH);                                       \
      bool vy1 = (y1 >= 0) && (y1 < HH);                                       \
      bool vx0 = (x0i >= 0) && (x0i < WW);                                     \
      bool vx1 = (x1 >= 0) && (x1 < WW);                                       \
      int yc0 = min(max(y0, 0), HH - 1), yc1 = min(max(y1, 0), HH - 1);        \
      int xc0 = min(max(x0i, 0), WW - 1), xc1 = min(max(x1, 0), WW - 1);       \
      cw00 = (1.f - ly) * (1.f - lx) * ((vy0 && vx0) ? msk : 0.f);             \
      cw01 = (1.f - ly) * lx         * ((vy0 && vx1) ? msk : 0.f);             \
      cw10 = ly * (1.f - lx)         * ((vy1 && vx0) ? msk : 0.f);             \
      cw11 = ly * lx                 * ((vy1 && vx1) ? msk : 0.f);             \
      cc00 = *(const uint4*)(xbc + (size_t)(yc0 * WW + xc0) * 64);             \
      cc01 = *(const uint4*)(xbc + (size_t)(yc0 * WW + xc1) * 64);             \
      cc10 = *(const uint4*)(xbc + (size_t)(yc1 * WW + xc0) * 64);             \
      cc11 = *(const uint4*)(xbc + (size_t)(yc1 * WW + xc1) * 64);             \
    } while (0)

    PREF_CORNERS(0);

#pragma unroll
    for (int kk = 0; kk < 9; ++kk) {
        const int cur = kk & 1;
        {
            char* wdst = mbase + cur * 4096;
            unsigned pk[4];
#pragma unroll
            for (int d = 0; d < 4; ++d) {
                unsigned u0 = (&cc00.x)[d], u1 = (&cc01.x)[d];
                unsigned u2 = (&cc10.x)[d], u3 = (&cc11.x)[d];
                float lo = cw00 * __builtin_bit_cast(float, u0 << 16)
                         + cw01 * __builtin_bit_cast(float, u1 << 16)
                         + cw10 * __builtin_bit_cast(float, u2 << 16)
                         + cw11 * __builtin_bit_cast(float, u3 << 16);
                float hi = cw00 * __builtin_bit_cast(float, u0 & 0xFFFF0000u)
                         + cw01 * __builtin_bit_cast(float, u1 & 0xFFFF0000u)
                         + cw10 * __builtin_bit_cast(float, u2 & 0xFFFF0000u)
                         + cw11 * __builtin_bit_cast(float, u3 & 0xFFFF0000u);
                pk[d] = (unsigned)f2bf(lo) | ((unsigned)f2bf(hi) << 16);
            }
            *(uint4*)(wdst + p1 * 128 + (((unsigned)(cg ^ (p1 & 7))) << 4)) = *(uint4*)pk;
        }
        if (kk < 8) PREF_CORNERS(kk + 1);
        asm volatile("s_waitcnt lgkmcnt(0)" ::: "memory");
        __builtin_amdgcn_s_barrier();
        __builtin_amdgcn_sched_barrier(0);
        const char* rb = mbase + cur * 4096;
#pragma unroll
        for (int sstep = 0; sstep < 2; ++sstep) {
            short8 a0 = *(const short8*)(arow0 + kk * 64 + sstep * 32);
            short8 a1 = *(const short8*)(arow1 + kk * 64 + sstep * 32);
            int kb = sstep * 4 + lk;
            short8 b0 = *(const short8*)(rb + rbA + ((kb ^ swA) << 4));
            short8 b1 = *(const short8*)(rb + rbB + ((kb ^ swB) << 4));
            acc00 = __builtin_amdgcn_mfma_f32_16x16x32_bf16(a0, b0, acc00, 0, 0, 0);
            acc01 = __builtin_amdgcn_mfma_f32_16x16x32_bf16(a0, b1, acc01, 0, 0, 0);
            acc10 = __builtin_amdgcn_mfma_f32_16x16x32_bf16(a1, b0, acc10, 0, 0, 0);
            acc11 = __builtin_amdgcn_mfma_f32_16x16x32_bf16(a1, b1, acc11, 0, 0, 0);
        }
    }
#undef PREF_CORNERS

    size_t outb = (size_t)b * COUT * HWP + (size_t)h * WW + w0;
#pragma unroll
    for (int of = 0; of < 2; ++of) {
        f32x4 aP = of ? acc10 : acc00;
        f32x4 aQ = of ? acc11 : acc01;
        int ocb = wid * 32 + of * 16 + lk * 4;
#pragma unroll
        for (int q = 0; q < 4; ++q) {
            int oc = ocb + q;
            float bi = bias[oc];
            out[outb + (size_t)oc * HWP + pA] = aP[q] + bi;
            out[outb + (size_t)oc * HWP + pB] = aQ[q] + bi;
        }
    }
}

extern "C" void kernel_launch(void* const* d_in, const int* in_sizes, int n_in,
                              void* d_out, int out_size, void* d_ws, size_t ws_size,
                              hipStream_t stream) {
    const float* x    = (const float*)d_in[0];
    const float* ow   = (const float*)d_in[1];
    const float* ob   = (const float*)d_in[2];
    const float* wgt  = (const float*)d_in[3];
    const float* bias = (const float*)d_in[4];
    float* out = (float*)d_out;
    char* ws = (char*)d_ws;

    unsigned short* wbf  = (unsigned short*)(ws + WBF_B);
    unsigned short* owbf = (unsigned short*)(ws + OWBF_B);
    unsigned short* xt   = (unsigned short*)(ws + XT_B);
    __half*         mh   = (__half*)(ws + META_B);

    hipLaunchKernelGGL(k_prep, dim3(2336), dim3(256), 0, stream,
                       x, wgt, ow, xt, wbf, owbf);
    if (ws_size >= WS_NEED3) {
        hipLaunchKernelGGL(k_offc, dim3(2048), dim3(256), 0, stream,
                           xt, owbf, ob, mh);
        hipLaunchKernelGGL(k_main64, dim3(1024), dim3(512), 0, stream,
                           xt, wbf, mh, bias, out);
    } else {
        hipLaunchKernelGGL(k_fused_v2, dim3(2048), dim3(256), 0, stream,
                           xt, wbf, owbf, ob, bias, out);
    }
}

// Round 24
// 80.632 us; speedup vs baseline: 1.0130x; 1.0130x over previous
//
#include <hip/hip_runtime.h>
#include <hip/hip_fp16.h>
#include <math.h>

#define HH   128
#define WW   128
#define HWP  16384      // H*W
#define CIN  64
#define COUT 128

typedef float  f32x4  __attribute__((ext_vector_type(4)));
typedef short  short8 __attribute__((ext_vector_type(8)));

// ws layout (bytes): wbf [128][576] bf16 @0; owbf [32][576] bf16 @147456;
// xt NHWC bf16 @221184 (8388608); meta fp16 [27][4][16384] @8609792 (3538944).
#define WBF_B    ((size_t)0)
#define OWBF_B   ((size_t)147456)
#define XT_B     ((size_t)221184)
#define META_B   ((size_t)8609792)
#define WS_NEED  ((size_t)8609792)
#define WS_NEED3 ((size_t)12148736)

__device__ inline unsigned short f2bf(float f) {
    unsigned u = __builtin_bit_cast(unsigned, f);
    return (unsigned short)((u + 0x7FFFu + ((u >> 16) & 1u)) >> 16);   // RNE
}

// ---------------- fused prep: xt transpose + weight transposes ----------------
__global__ __launch_bounds__(256) void k_prep(const float* __restrict__ x,
                                              const float* __restrict__ wgt,
                                              const float* __restrict__ ow,
                                              unsigned short* __restrict__ xt,
                                              unsigned short* __restrict__ wbf,
                                              unsigned short* __restrict__ owbf) {
    int t = threadIdx.x;
    if (blockIdx.x < 2048) {
        int bid  = blockIdx.x;
        int bid2 = (bid & 7) * 256 + (bid >> 3);      // T1 chunking (bijective)
        int cgrp = t & 7, px = t >> 3;
        int pix = bid2 * 32 + px;
        int b = pix >> 14, hw = pix & 16383;
        const float* xp = x + (size_t)b * CIN * HWP + (size_t)(cgrp * 8) * HWP + hw;
        unsigned pk[4];
#pragma unroll
        for (int d = 0; d < 4; ++d) {
            float lo = xp[(size_t)(2 * d) * HWP];
            float hi = xp[(size_t)(2 * d + 1) * HWP];
            pk[d] = (unsigned)f2bf(lo) | ((unsigned)f2bf(hi) << 16);
        }
        *(uint4*)(xt + (size_t)pix * 64 + cgrp * 8) = *(uint4*)pk;
    } else {
        int tid = (blockIdx.x - 2048) * 256 + t;
        {
            int oc = tid / 576;
            int r  = tid - oc * 576;
            int kk = r >> 6;
            int c  = r & 63;
            wbf[tid] = f2bf(wgt[((size_t)oc * CIN + c) * 9 + kk]);
        }
        if (tid < 32 * 576) {
            int oc  = tid / 576;
            int r   = tid - oc * 576;
            int tap = r >> 6;
            int c   = r & 63;
            owbf[tid] = (oc < 27) ? f2bf(ow[((size_t)oc * CIN + c) * 9 + tap]) : 0;
        }
    }
}

// ---------------- offset conv v3: LDS-staged context (proven R22) ----------
__global__ __launch_bounds__(256) void k_offc(const unsigned short* __restrict__ xt,
                                              const unsigned short* __restrict__ owbf,
                                              const float* __restrict__ ob,
                                              __half* __restrict__ meta_h) {
    __shared__ __align__(16) char ctx[13056];

    int blk0 = blockIdx.x;                       // 2048
    int blk  = (blk0 & 7) * 256 + (blk0 >> 3);   // T1 XCD chunking
    int b   = blk >> 9;
    int rem = blk & 511;
    int h   = rem >> 2;
    int w0  = (rem & 3) << 5;
    int t   = threadIdx.x;
    int l   = t & 63;
    int wid = t >> 6;
    int lm  = l & 15, lk = l >> 4;

    const unsigned short* xbt = xt + (size_t)b * HWP * 64;

#pragma unroll
    for (int c = 0; c < 4; ++c) {
        int j = c * 256 + t;
        if (j < 816) {
            int g   = j / 34;
            int px  = j - g * 34;
            int row = g >> 3;
            int cgj = g & 7;
            int yy = h - 1 + row;
            int xx = w0 - 1 + px;
            bool vld = (yy >= 0) && (yy < HH) && (xx >= 0) && (xx < WW);
            uint4 v = {0u, 0u, 0u, 0u};
            if (vld) v = *(const uint4*)(xbt + (size_t)(yy * WW + xx) * 64 + cgj * 8);
            *(uint4*)(ctx + (row * 34 + px) * 128 + ((cgj ^ (px & 7)) << 4)) = v;
        }
    }
    __syncthreads();

    int ocf = wid >> 1, pxf = wid & 1;
    int spx = pxf * 16 + lm;
    f32x4 sacc = {0.f, 0.f, 0.f, 0.f};
    const unsigned short* sab = owbf + (size_t)(ocf * 16 + lm) * 576 + lk * 8;

#pragma unroll
    for (int tap = 0; tap < 9; ++tap) {
        int ky = tap / 3, kx = tap % 3;
        int cpx = kx + spx;
        int crb = (ky * 34 + cpx) * 128;
        int csw = cpx & 7;
#pragma unroll
        for (int ch = 0; ch < 2; ++ch) {
            short8 a  = *(const short8*)(sab + tap * 64 + ch * 32);
            int kb = ch * 4 + lk;
            short8 bf = *(const short8*)(ctx + crb + (((unsigned)(kb ^ csw)) << 4));
            sacc = __builtin_amdgcn_mfma_f32_16x16x32_bf16(a, bf, sacc, 0, 0, 0);
        }
    }
    int hw = h * WW + w0 + spx;
#pragma unroll
    for (int q = 0; q < 4; ++q) {
        int oc = ocf * 16 + lk * 4 + q;
        if (oc < 27) {
            float v = sacc[q] + ob[oc];
            int comp, kk;
            if (oc < 18) { comp = oc & 1; kk = oc >> 1; }
            else         { comp = 2; kk = oc - 18; v = 1.f / (1.f + expf(-v)); }
            meta_h[((size_t)(comp * 9 + kk) * 4 + b) * HWP + hw] = __float2half(v);
        }
    }
}

// ================= k_main: 32px x 128oc (R22 exact, proven 52.4us) ===========
__global__ __launch_bounds__(256) void k_main(const unsigned short* __restrict__ xt,
                                              const unsigned short* __restrict__ wbf,
                                              const __half* __restrict__ meta_h,
                                              const float* __restrict__ bias,
                                              float* __restrict__ out) {
    __shared__ __align__(16) char smem[11648];
    char*  mbase  = smem;
    float* meta_s = (float*)(smem + 8192);

    int blk0 = blockIdx.x;
    int blk  = (blk0 & 7) * 256 + (blk0 >> 3);   // T1 XCD chunking
    int b   = blk >> 9;
    int rem = blk & 511;
    int h   = rem >> 2;
    int w0  = (rem & 3) << 5;
    int t   = threadIdx.x;

    int p1 = t >> 3;
    int cg = t & 7;
    int l  = t & 63;
    int wid = t >> 6;
    int lm = l & 15, lk = l >> 4;

    const unsigned short* xbt = xt + (size_t)b * HWP * 64;

    {
        int base_hw = h * WW + w0;
        for (int j = t; j < 864; j += 256) {
            int px = j & 31;
            int ck = j >> 5;
            float v = __half2float(meta_h[((size_t)ck * 4 + b) * HWP + base_hw + px]);
            int comp = ck / 9, kk = ck - comp * 9;
            meta_s[comp * 288 + kk * 32 + px] = v;
        }
    }
    __syncthreads();

    f32x4 acc00 = {0.f,0.f,0.f,0.f};
    f32x4 acc01 = {0.f,0.f,0.f,0.f};
    f32x4 acc10 = {0.f,0.f,0.f,0.f};
    f32x4 acc11 = {0.f,0.f,0.f,0.f};

    const unsigned short* arow0 = wbf + (size_t)(wid * 32 + lm) * 576 + lk * 8;
    const unsigned short* arow1 = arow0 + 16 * 576;

    int pA = lm, pB = lm + 16;
    int rbA = pA * 128, rbB = pB * 128;
    int swA = pA & 7,   swB = pB & 7;

    uint4 cc00, cc01, cc10, cc11;
    float cw00, cw01, cw10, cw11;

    const unsigned short* xbc = xbt + cg * 8;

#define PREF_CORNERS(KK) do {                                                  \
      int ky_ = (KK) / 3, kx_ = (KK) % 3;                                      \
      float offy = meta_s[(KK) * 32 + p1];                                     \
      float offx = meta_s[288 + (KK) * 32 + p1];                               \
      float msk  = meta_s[576 + (KK) * 32 + p1];                               \
      float py = (float)(h - 1 + ky_) + offy;                                  \
      float px = (float)(w0 + p1 - 1 + kx_) + offx;                            \
      float y0f = floorf(py), x0f = floorf(px);                                \
      float ly = py - y0f, lx = px - x0f;                                      \
      int y0 = (int)y0f, x0i = (int)x0f;                                       \
      int y1 = y0 + 1, x1 = x0i + 1;                                           \
      bool vy0 = (y0 >= 0) && (y0 < HH);                                       \
      bool vy1 = (y1 >= 0) && (y1 < HH);                                       \
      bool vx0 = (x0i >= 0) && (x0i < WW);                                     \
      bool vx1 = (x1 >= 0) && (x1 < WW);                                       \
      int yc0 = min(max(y0, 0), HH - 1), yc1 = min(max(y1, 0), HH - 1);        \
      int xc0 = min(max(x0i, 0), WW - 1), xc1 = min(max(x1, 0), WW - 1);       \
      cw00 = (1.f - ly) * (1.f - lx) * ((vy0 && vx0) ? msk : 0.f);             \
      cw01 = (1.f - ly) * lx         * ((vy0 && vx1) ? msk : 0.f);             \
      cw10 = ly * (1.f - lx)         * ((vy1 && vx0) ? msk : 0.f);             \
      cw11 = ly * lx                 * ((vy1 && vx1) ? msk : 0.f);             \
      cc00 = *(const uint4*)(xbc + (size_t)(yc0 * WW + xc0) * 64);             \
      cc01 = *(const uint4*)(xbc + (size_t)(yc0 * WW + xc1) * 64);             \
      cc10 = *(const uint4*)(xbc + (size_t)(yc1 * WW + xc0) * 64);             \
      cc11 = *(const uint4*)(xbc + (size_t)(yc1 * WW + xc1) * 64);             \
    } while (0)

    PREF_CORNERS(0);

#pragma unroll
    for (int kk = 0; kk < 9; ++kk) {
        const int cur = kk & 1;
        {
            char* wdst = mbase + cur * 4096;
            unsigned pk[4];
#pragma unroll
            for (int d = 0; d < 4; ++d) {
                unsigned u0 = (&cc00.x)[d], u1 = (&cc01.x)[d];
                unsigned u2 = (&cc10.x)[d], u3 = (&cc11.x)[d];
                float lo = cw00 * __builtin_bit_cast(float, u0 << 16)
                         + cw01 * __builtin_bit_cast(float, u1 << 16)
                         + cw10 * __builtin_bit_cast(float, u2 << 16)
                         + cw11 * __builtin_bit_cast(float, u3 << 16);
                float hi = cw00 * __builtin_bit_cast(float, u0 & 0xFFFF0000u)
                         + cw01 * __builtin_bit_cast(float, u1 & 0xFFFF0000u)
                         + cw10 * __builtin_bit_cast(float, u2 & 0xFFFF0000u)
                         + cw11 * __builtin_bit_cast(float, u3 & 0xFFFF0000u);
                pk[d] = (unsigned)f2bf(lo) | ((unsigned)f2bf(hi) << 16);
            }
            *(uint4*)(wdst + p1 * 128 + (((unsigned)(cg ^ (p1 & 7))) << 4)) = *(uint4*)pk;
        }
        if (kk < 8) PREF_CORNERS(kk + 1);
        asm volatile("s_waitcnt lgkmcnt(0)" ::: "memory");
        __builtin_amdgcn_s_barrier();
        __builtin_amdgcn_sched_barrier(0);
        const char* rb = mbase + cur * 4096;
#pragma unroll
        for (int sstep = 0; sstep < 2; ++sstep) {
            short8 a0 = *(const short8*)(arow0 + kk * 64 + sstep * 32);
            short8 a1 = *(const short8*)(arow1 + kk * 64 + sstep * 32);
            int kb = sstep * 4 + lk;
            short8 b0 = *(const short8*)(rb + rbA + ((kb ^ swA) << 4));
            short8 b1 = *(const short8*)(rb + rbB + ((kb ^ swB) << 4));
            acc00 = __builtin_amdgcn_mfma_f32_16x16x32_bf16(a0, b0, acc00, 0, 0, 0);
            acc01 = __builtin_amdgcn_mfma_f32_16x16x32_bf16(a0, b1, acc01, 0, 0, 0);
            acc10 = __builtin_amdgcn_mfma_f32_16x16x32_bf16(a1, b0, acc10, 0, 0, 0);
            acc11 = __builtin_amdgcn_mfma_f32_16x16x32_bf16(a1, b1, acc11, 0, 0, 0);
        }
    }
#undef PREF_CORNERS

    size_t outb = (size_t)b * COUT * HWP + (size_t)h * WW + w0;
#pragma unroll
    for (int of = 0; of < 2; ++of) {
        f32x4 aP = of ? acc10 : acc00;
        f32x4 aQ = of ? acc11 : acc01;
        int ocb = wid * 32 + of * 16 + lk * 4;
#pragma unroll
        for (int q = 0; q < 4; ++q) {
            int oc = ocb + q;
            float bi = bias[oc];
            out[outb + (size_t)oc * HWP + pA] = aP[q] + bi;
            out[outb + (size_t)oc * HWP + pB] = aQ[q] + bi;
        }
    }
}

// ================= v2 fused (R17 exact; fallback if ws too small) ============
__global__ __launch_bounds__(256) void k_fused_v2(const unsigned short* __restrict__ xt,
                                                  const unsigned short* __restrict__ wbf,
                                                  const unsigned short* __restrict__ owbf,
                                                  const float* __restrict__ ob,
                                                  const float* __restrict__ bias,
                                                  float* __restrict__ out) {
    __shared__ __align__(16) char smem[11648];
    char*  mbase  = smem;
    float* meta_s = (float*)(smem + 8192);

    int blk0 = blockIdx.x;
    int blk  = (blk0 & 7) * 256 + (blk0 >> 3);
    int b   = blk >> 9;
    int rem = blk & 511;
    int h   = rem >> 2;
    int w0  = (rem & 3) << 5;
    int t   = threadIdx.x;

    int p1 = t >> 3;
    int cg = t & 7;
    int l  = t & 63;
    int wid = t >> 6;
    int lm = l & 15, lk = l >> 4;

    const unsigned short* xbt = xt + (size_t)b * HWP * 64;

    int ocf = wid >> 1, pxf = wid & 1;
    int spx = pxf * 16 + lm;
    f32x4 sacc = {0.f, 0.f, 0.f, 0.f};
    const unsigned short* sab = owbf + (size_t)(ocf * 16 + lm) * 576 + lk * 8;

#pragma unroll
    for (int tap = 0; tap < 9; ++tap) {
        int ky = tap / 3, kx = tap % 3;
        int yy = h - 1 + ky;
        int xx = w0 - 1 + kx + spx;
        bool vld = (yy >= 0) && (yy < HH) && (xx >= 0) && (xx < WW);
        int yc = min(max(yy, 0), HH - 1), xc = min(max(xx, 0), WW - 1);
        const unsigned short* bp = xbt + (size_t)(yc * WW + xc) * 64 + lk * 8;
#pragma unroll
        for (int ch = 0; ch < 2; ++ch) {
            short8 a = *(const short8*)(sab + tap * 64 + ch * 32);
            uint4 v = *(const uint4*)(bp + ch * 32);
            v.x = vld ? v.x : 0u;  v.y = vld ? v.y : 0u;
            v.z = vld ? v.z : 0u;  v.w = vld ? v.w : 0u;
            sacc = __builtin_amdgcn_mfma_f32_16x16x32_bf16(a, __builtin_bit_cast(short8, v), sacc, 0, 0, 0);
        }
    }
#pragma unroll
    for (int q = 0; q < 4; ++q) {
        int oc = ocf * 16 + lk * 4 + q;
        if (oc < 27) {
            float v = sacc[q] + ob[oc];
            if (oc < 18) {
                meta_s[(oc & 1) * 288 + (oc >> 1) * 32 + spx] = v;
            } else {
                meta_s[2 * 288 + (oc - 18) * 32 + spx] = 1.f / (1.f + expf(-v));
            }
        }
    }
    __syncthreads();

    f32x4 acc00 = {0.f,0.f,0.f,0.f};
    f32x4 acc01 = {0.f,0.f,0.f,0.f};
    f32x4 acc10 = {0.f,0.f,0.f,0.f};
    f32x4 acc11 = {0.f,0.f,0.f,0.f};

    const unsigned short* arow0 = wbf + (size_t)(wid * 32 + lm) * 576 + lk * 8;
    const unsigned short* arow1 = arow0 + 16 * 576;

    int pA = lm, pB = lm + 16;
    int rbA = pA * 128, rbB = pB * 128;
    int swA = pA & 7,   swB = pB & 7;

    uint4 cc00, cc01, cc10, cc11;
    float cw00, cw01, cw10, cw11;

    const unsigned short* xbc = xbt + cg * 8;

#define PREF_CORNERS(KK) do {                                                  \
      int ky_ = (KK) / 3, kx_ = (KK) % 3;                                      \
      float offy = meta_s[(KK) * 32 + p1];                                     \
      float offx = meta_s[288 + (KK) * 32 + p1];                               \
      float msk  = meta_s[576 + (KK) * 32 + p1];                               \
      float py = (float)(h - 1 + ky_) + offy;                                  \
      float px = (float)(w0 + p1 - 1 + kx_) + offx;                            \
      float y0f = floorf(py), x0f = floorf(px);                                \
      float ly = py - y0f, lx = px - x0f;                                      \
      int y0 = (int)y0f, x0i = (int)x0f;                                       \
      int y1 = y0 + 1, x1 = x0i + 1;                                           \
      bool vy0 = (y0 >= 0) && (y0 < HH);                                       \
      bool vy1 = (y1 >= 0) && (y1 < HH);                                       \
      bool vx0 = (x0i >= 0) && (x0i < WW);                                     \
      bool vx1 = (x1 >= 0) && (x1 < WW);                                       \
      int yc0 = min(max(y0, 0), HH - 1), yc1 = min(max(y1, 0), HH - 1);        \
      int xc0 = min(max(x0i, 0), WW - 1), xc1 = min(max(x1, 0), WW - 1);       \
      cw00 = (1.f - ly) * (1.f - lx) * ((vy0 && vx0) ? msk : 0.f);             \
      cw01 = (1.f - ly) * lx         * ((vy0 && vx1) ? msk : 0.f);             \
      cw10 = ly * (1.f - lx)         * ((vy1 && vx0) ? msk : 0.f);             \
      cw11 = ly * lx                 * ((vy1 && vx1) ? msk : 0.f);             \
      cc00 = *(const uint4*)(xbc + (size_t)(yc0 * WW + xc0) * 64);             \
      cc01 = *(const uint4*)(xbc + (size_t)(yc0 * WW + xc1) * 64);             \
      cc10 = *(const uint4*)(xbc + (size_t)(yc1 * WW + xc0) * 64);             \
      cc11 = *(const uint4*)(xbc + (size_t)(yc1 * WW + xc1) * 64);             \
    } while (0)

    PREF_CORNERS(0);

#pragma unroll
    for (int kk = 0; kk < 9; ++kk) {
        const int cur = kk & 1;
        {
            char* wdst = mbase + cur * 4096;
            unsigned pk[4];
#pragma unroll
            for (int d = 0; d < 4; ++d) {
                unsigned u0 = (&cc00.x)[d], u1 = (&cc01.x)[d];
                unsigned u2 = (&cc10.x)[d], u3 = (&cc11.x)[d];
                float lo = cw00 * __builtin_bit_cast(float, u0 << 16)
                         + cw01 * __builtin_bit_cast(float, u1 << 16)
                         + cw10 * __builtin_bit_cast(float, u2 << 16)
                         + cw11 * __builtin_bit_cast(float, u3 << 16);
                float hi = cw00 * __builtin_bit_cast(float, u0 & 0xFFFF0000u)
                         + cw01 * __builtin_bit_cast(float, u1 & 0xFFFF0000u)
                         + cw10 * __builtin_bit_cast(float, u2 & 0xFFFF0000u)
                         + cw11 * __builtin_bit_cast(float, u3 & 0xFFFF0000u);
                pk[d] = (unsigned)f2bf(lo) | ((unsigned)f2bf(hi) << 16);
            }
            *(uint4*)(wdst + p1 * 128 + (((unsigned)(cg ^ (p1 & 7))) << 4)) = *(uint4*)pk;
        }
        if (kk < 8) PREF_CORNERS(kk + 1);
        asm volatile("s_waitcnt lgkmcnt(0)" ::: "memory");
        __builtin_amdgcn_s_barrier();
        __builtin_amdgcn_sched_barrier(0);
        const char* rb = mbase + cur * 4096;
#pragma unroll
        for (int sstep = 0; sstep < 2; ++sstep) {
            short8 a0 = *(const short8*)(arow0 + kk * 64 + sstep * 32);
            short8 a1 = *(const short8*)(arow1 + kk * 64 + sstep * 32);
            int kb = sstep * 4 + lk;
            short8 b0 = *(const short8*)(rb + rbA + ((kb ^ swA) << 4));
            short8 b1 = *(const short8*)(rb + rbB + ((kb ^ swB) << 4));
            acc00 = __builtin_amdgcn_mfma_f32_16x16x32_bf16(a0, b0, acc00, 0, 0, 0);
            acc01 = __builtin_amdgcn_mfma_f32_16x16x32_bf16(a0, b1, acc01, 0, 0, 0);
            acc10 = __builtin_amdgcn_mfma_f32_16x16x32_bf16(a1, b0, acc10, 0, 0, 0);
            acc11 = __builtin_amdgcn_mfma_f32_16x16x32_bf16(a1, b1, acc11, 0, 0, 0);
        }
    }
#undef PREF_CORNERS

    size_t outb = (size_t)b * COUT * HWP + (size_t)h * WW + w0;
#pragma unroll
    for (int of = 0; of < 2; ++of) {
        f32x4 aP = of ? acc10 : acc00;
        f32x4 aQ = of ? acc11 : acc01;
        int ocb = wid * 32 + of * 16 + lk * 4;
#pragma unroll
        for (int q = 0; q < 4; ++q) {
            int oc = ocb + q;
            float bi = bias[oc];
            out[outb + (size_t)oc * HWP + pA] = aP[q] + bi;
            out[outb + (size_t)oc * HWP + pB] = aQ[q] + bi;
        }
    }
}

extern "C" void kernel_launch(void* const* d_in, const int* in_sizes, int n_in,
                              void* d_out, int out_size, void* d_ws, size_t ws_size,
                              hipStream_t stream) {
    const float* x    = (const float*)d_in[0];
    const float* ow   = (const float*)d_in[1];
    const float* ob   = (const float*)d_in[2];
    const float* wgt  = (const float*)d_in[3];
    const float* bias = (const float*)d_in[4];
    float* out = (float*)d_out;
    char* ws = (char*)d_ws;

    unsigned short* wbf  = (unsigned short*)(ws + WBF_B);
    unsigned short* owbf = (unsigned short*)(ws + OWBF_B);
    unsigned short* xt   = (unsigned short*)(ws + XT_B);
    __half*         mh   = (__half*)(ws + META_B);

    hipLaunchKernelGGL(k_prep, dim3(2336), dim3(256), 0, stream,
                       x, wgt, ow, xt, wbf, owbf);
    if (ws_size >= WS_NEED3) {
        hipLaunchKernelGGL(k_offc, dim3(2048), dim3(256), 0, stream,
                           xt, owbf, ob, mh);
        hipLaunchKernelGGL(k_main, dim3(2048), dim3(256), 0, stream,
                           xt, wbf, mh, bias, out);
    } else {
        hipLaunchKernelGGL(k_fused_v2, dim3(2048), dim3(256), 0, stream,
                           xt, wbf, owbf, ob, bias, out);
    }
}